// Round 3
// baseline (3898.441 us; speedup 1.0000x reference)
//
#include <hip/hip_runtime.h>
#include <hip/hip_bf16.h>

#define NNODE 8192
#define DEG   32
#define DIN   256
#define EDIM  64
#define KC    576            // 2*DIN + EDIM
#define DD    512            // internal width D
#define NH    8
#define MEDGE (NNODE*DEG)
#define EXP   520            // 512 + 8 bf16 row pad (16B aligned rows)

typedef __attribute__((ext_vector_type(8))) short short8;
typedef __attribute__((ext_vector_type(4))) short short4v;
typedef __attribute__((ext_vector_type(4))) float floatx4;
typedef __attribute__((ext_vector_type(4))) unsigned int uint4v;
typedef unsigned int u32;

__device__ __forceinline__ ushort f2bf(float f) {
  union { float f; unsigned int i; } v; v.f = f;
  return (ushort)((v.i + 0x7fffu + ((v.i >> 16) & 1u)) >> 16);
}
__device__ __forceinline__ u32 pk2(float a, float b) {
  return (u32)f2bf(a) | ((u32)f2bf(b) << 16);
}
__device__ __forceinline__ float gelu_f(float z) {
  return 0.5f * z * (1.0f + erff(z * 0.70710678118654752f));
}
__device__ __forceinline__ floatx4 zero4() { floatx4 v = {0.f, 0.f, 0.f, 0.f}; return v; }

// load 8 consecutive fp32 -> bf16 half-fragment
__device__ __forceinline__ short8 ld_cvt8(const float* __restrict__ p) {
  floatx4 a = *(const floatx4*)(p);
  floatx4 b = *(const floatx4*)(p + 4);
  short8 r;
  r[0] = (short)f2bf(a[0]); r[1] = (short)f2bf(a[1]);
  r[2] = (short)f2bf(a[2]); r[3] = (short)f2bf(a[3]);
  r[4] = (short)f2bf(b[0]); r[5] = (short)f2bf(b[1]);
  r[6] = (short)f2bf(b[2]); r[7] = (short)f2bf(b[3]);
  return r;
}

#define MFMA16(a, b, c) __builtin_amdgcn_mfma_f32_16x16x32_bf16((a), (b), (c), 0, 0, 0)

// D-layout -> A/B-frag-layout in-register transform.
// Source packed tiles T[tile][p]: lane(lg',lr') dword p = bf16 pair of
// M[tile*16 + lg'*4 + 2p + {0,1}][lr'-col]. Target frag: lane(lg,lr) dword dj =
// M-pair at rows base+8lg+2dj from source lane (2(lg&1)+(dj>>1))*16+lr,
// tile = (lg>>1) among {T0,T1}.
__device__ __forceinline__ u32 bpsel(int a, u32 v0, u32 v1, bool hi) {
  u32 x0 = (u32)__builtin_amdgcn_ds_bpermute(a, (int)v0);
  u32 x1 = (u32)__builtin_amdgcn_ds_bpermute(a, (int)v1);
  return hi ? x1 : x0;
}
__device__ __forceinline__ short8 frag4(int a0, int a1, bool hi,
                                        u32 t00, u32 t01, u32 t10, u32 t11) {
  uint4v r;
  r[0] = bpsel(a0, t00, t10, hi);
  r[1] = bpsel(a0, t01, t11, hi);
  r[2] = bpsel(a1, t00, t10, hi);
  r[3] = bpsel(a1, t01, t11, hi);
  union { uint4v u; short8 s; } c; c.u = r; return c.s;
}

__global__ __launch_bounds__(512, 4) void nt_fused(
    const float* __restrict__ x,  const float* __restrict__ ea,
    const int*   __restrict__ e,
    const ushort* __restrict__ Wc, const float* __restrict__ bc,
    const ushort* __restrict__ Wi, const float* __restrict__ bi,
    const ushort* __restrict__ Wo, const float* __restrict__ bo,
    float* __restrict__ out)
{
  __shared__ __align__(16) ushort sEX[DEG * EXP];   // ex  [32][512] bf16
  __shared__ __align__(16) ushort sAO[DEG * EXP];   // attn out [32][512] bf16

  const int node = blockIdx.x;
  const int m0   = node * DEG;
  const int tid  = threadIdx.x;
  const int w    = tid >> 6;    // wave 0..7 : head w, col slice w*64
  const int l    = tid & 63;
  const int lr   = l & 15;
  const int lg   = l >> 4;

  const int src = e[m0];
  const int dA0 = e[MEDGE + m0 + lr];
  const int dA1 = e[MEDGE + m0 + 16 + lr];

  // ================= GEMM1: ex = gelu(gelu(feat @ Wc^T + bc)) =================
  {
    floatx4 acc0[4], acc1[4];
    #pragma unroll
    for (int nt = 0; nt < 4; ++nt) { acc0[nt] = zero4(); acc1[nt] = zero4(); }

    const float* xsrc = x + (size_t)src * DIN;
    #pragma unroll
    for (int s = 0; s < 8; ++s) {          // k 0..255 : x[src] (both M-tiles equal)
      short8 af = ld_cvt8(xsrc + s * 32 + lg * 8);
      #pragma unroll
      for (int nt = 0; nt < 4; ++nt) {
        const int col = w * 64 + nt * 16 + lr;
        short8 bf = *(const short8*)(Wc + (size_t)col * KC + s * 32 + lg * 8);
        acc0[nt] = MFMA16(af, bf, acc0[nt]);
      }
    }
    #pragma unroll
    for (int nt = 0; nt < 4; ++nt) acc1[nt] = acc0[nt];

    const float* xd0 = x + (size_t)dA0 * DIN;
    const float* xd1 = x + (size_t)dA1 * DIN;
    #pragma unroll
    for (int s = 0; s < 8; ++s) {          // k 256..511 : x[dst]
      short8 a0f = ld_cvt8(xd0 + s * 32 + lg * 8);
      short8 a1f = ld_cvt8(xd1 + s * 32 + lg * 8);
      #pragma unroll
      for (int nt = 0; nt < 4; ++nt) {
        const int col = w * 64 + nt * 16 + lr;
        short8 bf = *(const short8*)(Wc + (size_t)col * KC + 256 + s * 32 + lg * 8);
        acc0[nt] = MFMA16(a0f, bf, acc0[nt]);
        acc1[nt] = MFMA16(a1f, bf, acc1[nt]);
      }
    }
    const float* ea0 = ea + (size_t)(m0 + lr) * EDIM;
    const float* ea1 = ea + (size_t)(m0 + 16 + lr) * EDIM;
    #pragma unroll
    for (int s = 0; s < 2; ++s) {          // k 512..575 : edge_attr
      short8 a0f = ld_cvt8(ea0 + s * 32 + lg * 8);
      short8 a1f = ld_cvt8(ea1 + s * 32 + lg * 8);
      #pragma unroll
      for (int nt = 0; nt < 4; ++nt) {
        const int col = w * 64 + nt * 16 + lr;
        short8 bf = *(const short8*)(Wc + (size_t)col * KC + 512 + s * 32 + lg * 8);
        acc0[nt] = MFMA16(a0f, bf, acc0[nt]);
        acc1[nt] = MFMA16(a1f, bf, acc1[nt]);
      }
    }
    #pragma unroll
    for (int nt = 0; nt < 4; ++nt) {
      const int col = w * 64 + nt * 16 + lr;
      const float bias = bc[col];
      #pragma unroll
      for (int i = 0; i < 4; ++i) {
        sEX[(lg * 4 + i) * EXP + col]      = f2bf(gelu_f(gelu_f(acc0[nt][i] + bias)));
        sEX[(16 + lg * 4 + i) * EXP + col] = f2bf(gelu_f(gelu_f(acc1[nt][i] + bias)));
      }
    }
  }
  __syncthreads();   // barrier #1: sEX complete

  // ================= attention, head w, fully per-wave ======================
  const int qb = w * 64, kb = 512 + w * 64, vb = 1024 + w * 64;

  // ---- phase A: Q' = Wq·ex^T, K' = Wk·ex^T (transposed: rows=qkv-col, cols=edge)
  floatx4 qacc[4][2], kacc[4][2];
  #pragma unroll
  for (int mt = 0; mt < 4; ++mt)
    #pragma unroll
    for (int nt = 0; nt < 2; ++nt) { qacc[mt][nt] = zero4(); kacc[mt][nt] = zero4(); }

  #pragma unroll
  for (int ks = 0; ks < 16; ++ks) {
    short8 ex0 = *(const short8*)(&sEX[lr * EXP + ks * 32 + lg * 8]);
    short8 ex1 = *(const short8*)(&sEX[(16 + lr) * EXP + ks * 32 + lg * 8]);
    #pragma unroll
    for (int mt = 0; mt < 4; ++mt) {
      short8 wq = *(const short8*)(Wi + (size_t)(qb + mt * 16 + lr) * DD + ks * 32 + lg * 8);
      short8 wk = *(const short8*)(Wi + (size_t)(kb + mt * 16 + lr) * DD + ks * 32 + lg * 8);
      qacc[mt][0] = MFMA16(wq, ex0, qacc[mt][0]);
      qacc[mt][1] = MFMA16(wq, ex1, qacc[mt][1]);
      kacc[mt][0] = MFMA16(wk, ex0, kacc[mt][0]);
      kacc[mt][1] = MFMA16(wk, ex1, kacc[mt][1]);
    }
  }
  u32 qp[4][2][2], kp[4][2][2];
  #pragma unroll
  for (int mt = 0; mt < 4; ++mt) {
    float bq[4], bk[4];
    #pragma unroll
    for (int i = 0; i < 4; ++i) {
      bq[i] = bi[qb + mt * 16 + lg * 4 + i];
      bk[i] = bi[kb + mt * 16 + lg * 4 + i];
    }
    #pragma unroll
    for (int nt = 0; nt < 2; ++nt) {
      floatx4 vq = qacc[mt][nt], vk = kacc[mt][nt];
      qp[mt][nt][0] = pk2(vq[0] + bq[0], vq[1] + bq[1]);
      qp[mt][nt][1] = pk2(vq[2] + bq[2], vq[3] + bq[3]);
      kp[mt][nt][0] = pk2(vk[0] + bk[0], vk[1] + bk[1]);
      kp[mt][nt][1] = pk2(vk[2] + bk[2], vk[3] + bk[3]);
    }
  }

  // ---- phase B: V normal (rows=edge, cols=vcol)
  floatx4 vacc[2][4];
  #pragma unroll
  for (int mt = 0; mt < 2; ++mt)
    #pragma unroll
    for (int nt = 0; nt < 4; ++nt) vacc[mt][nt] = zero4();
  #pragma unroll
  for (int ks = 0; ks < 16; ++ks) {
    short8 ex0 = *(const short8*)(&sEX[lr * EXP + ks * 32 + lg * 8]);
    short8 ex1 = *(const short8*)(&sEX[(16 + lr) * EXP + ks * 32 + lg * 8]);
    #pragma unroll
    for (int nt = 0; nt < 4; ++nt) {
      short8 wv = *(const short8*)(Wi + (size_t)(vb + nt * 16 + lr) * DD + ks * 32 + lg * 8);
      vacc[0][nt] = MFMA16(ex0, wv, vacc[0][nt]);
      vacc[1][nt] = MFMA16(ex1, wv, vacc[1][nt]);
    }
  }
  u32 vp[2][4][2];
  #pragma unroll
  for (int nt = 0; nt < 4; ++nt) {
    const float bv = bi[vb + nt * 16 + lr];
    #pragma unroll
    for (int mt = 0; mt < 2; ++mt) {
      floatx4 v = vacc[mt][nt];
      vp[mt][nt][0] = pk2(v[0] + bv, v[1] + bv);
      vp[mt][nt][1] = pk2(v[2] + bv, v[3] + bv);
    }
  }

  // ---- scores' [k-edge][q-edge] = K·Q^T-style, then softmax over k-edges
  const int pa0 = ((2 * (lg & 1)) * 16 + lr) * 4;
  const int pa1 = pa0 + 64;
  const bool hi = ((lg >> 1) & 1) != 0;

  floatx4 sacc[2][2];
  #pragma unroll
  for (int mt = 0; mt < 2; ++mt)
    #pragma unroll
    for (int nt = 0; nt < 2; ++nt) sacc[mt][nt] = zero4();
  #pragma unroll
  for (int kt = 0; kt < 2; ++kt) {
    short8 afr0 = frag4(pa0, pa1, hi, kp[2*kt][0][0], kp[2*kt][0][1], kp[2*kt+1][0][0], kp[2*kt+1][0][1]);
    short8 afr1 = frag4(pa0, pa1, hi, kp[2*kt][1][0], kp[2*kt][1][1], kp[2*kt+1][1][0], kp[2*kt+1][1][1]);
    short8 bfr0 = frag4(pa0, pa1, hi, qp[2*kt][0][0], qp[2*kt][0][1], qp[2*kt+1][0][0], qp[2*kt+1][0][1]);
    short8 bfr1 = frag4(pa0, pa1, hi, qp[2*kt][1][0], qp[2*kt][1][1], qp[2*kt+1][1][0], qp[2*kt+1][1][1]);
    sacc[0][0] = MFMA16(afr0, bfr0, sacc[0][0]);
    sacc[0][1] = MFMA16(afr0, bfr1, sacc[0][1]);
    sacc[1][0] = MFMA16(afr1, bfr0, sacc[1][0]);
    sacc[1][1] = MFMA16(afr1, bfr1, sacc[1][1]);
  }

  u32 pp[2][2][2];   // [ke-tile][qe-tile][p]
  #pragma unroll
  for (int nt = 0; nt < 2; ++nt) {
    float s[2][4];
    float mx = -1e30f;
    #pragma unroll
    for (int mt = 0; mt < 2; ++mt)
      #pragma unroll
      for (int i = 0; i < 4; ++i) {
        s[mt][i] = sacc[mt][nt][i] * 0.125f;
        mx = fmaxf(mx, s[mt][i]);
      }
    mx = fmaxf(mx, __shfl_xor(mx, 16));
    mx = fmaxf(mx, __shfl_xor(mx, 32));
    float sm = 0.f;
    #pragma unroll
    for (int mt = 0; mt < 2; ++mt)
      #pragma unroll
      for (int i = 0; i < 4; ++i) { s[mt][i] = expf(s[mt][i] - mx); sm += s[mt][i]; }
    sm += __shfl_xor(sm, 16);
    sm += __shfl_xor(sm, 32);
    const float inv = 1.0f / sm;
    #pragma unroll
    for (int mt = 0; mt < 2; ++mt) {
      pp[mt][nt][0] = pk2(s[mt][0] * inv, s[mt][1] * inv);
      pp[mt][nt][1] = pk2(s[mt][2] * inv, s[mt][3] * inv);
    }
  }

  // ---- PV: o[q-edge][vcol] = P·V -> sAO cols [w*64, w*64+64)
  {
    short8 paf[2], vbf[4];
    #pragma unroll
    for (int mt = 0; mt < 2; ++mt)
      paf[mt] = frag4(pa0, pa1, hi, pp[0][mt][0], pp[0][mt][1], pp[1][mt][0], pp[1][mt][1]);
    #pragma unroll
    for (int nt = 0; nt < 4; ++nt)
      vbf[nt] = frag4(pa0, pa1, hi, vp[0][nt][0], vp[0][nt][1], vp[1][nt][0], vp[1][nt][1]);
    #pragma unroll
    for (int mt = 0; mt < 2; ++mt)
      #pragma unroll
      for (int nt = 0; nt < 4; ++nt) {
        floatx4 o = MFMA16(paf[mt], vbf[nt], zero4());
        #pragma unroll
        for (int i = 0; i < 4; ++i)
          sAO[(mt * 16 + lg * 4 + i) * EXP + w * 64 + nt * 16 + lr] = f2bf(o[i]);
      }
  }
  __syncthreads();   // barrier #2: sAO complete

  // ================= GEMM3: h = gelu(AO @ Wo^T + bo) + weighted-mean agg =====
  floatx4 h3[2][4];
  #pragma unroll
  for (int mt = 0; mt < 2; ++mt)
    #pragma unroll
    for (int nt = 0; nt < 4; ++nt) h3[mt][nt] = zero4();
  #pragma unroll
  for (int ks = 0; ks < 16; ++ks) {
    short8 a0f = *(const short8*)(&sAO[lr * EXP + ks * 32 + lg * 8]);
    short8 a1f = *(const short8*)(&sAO[(16 + lr) * EXP + ks * 32 + lg * 8]);
    #pragma unroll
    for (int nt = 0; nt < 4; ++nt) {
      const int col = w * 64 + nt * 16 + lr;
      short8 bf = *(const short8*)(Wo + (size_t)col * DD + ks * 32 + lg * 8);
      h3[0][nt] = MFMA16(a0f, bf, h3[0][nt]);
      h3[1][nt] = MFMA16(a1f, bf, h3[1][nt]);
    }
  }
  #pragma unroll
  for (int nt = 0; nt < 4; ++nt) {
    const float bias = bo[w * 64 + nt * 16 + lr];
    #pragma unroll
    for (int i = 0; i < 4; ++i) {
      h3[0][nt][i] = gelu_f(h3[0][nt][i] + bias);
      h3[1][nt][i] = gelu_f(h3[1][nt][i] + bias);
    }
  }
  // logits (head w) = mean over ch1 (tiles 2,3): reduce across lr lanes
  float lgA[2][4];
  #pragma unroll
  for (int mt = 0; mt < 2; ++mt)
    #pragma unroll
    for (int i = 0; i < 4; ++i) {
      float tA = h3[mt][2][i] + h3[mt][3][i];
      #pragma unroll
      for (int d2 = 1; d2 < 16; d2 <<= 1) tA += __shfl_xor(tA, d2);
      lgA[mt][i] = tA * (1.0f / 32.0f);
    }
  // alpha = softmax over the 32 edges (per head)
  float mxA = -1e30f;
  #pragma unroll
  for (int mt = 0; mt < 2; ++mt)
    #pragma unroll
    for (int i = 0; i < 4; ++i) mxA = fmaxf(mxA, lgA[mt][i]);
  mxA = fmaxf(mxA, __shfl_xor(mxA, 16));
  mxA = fmaxf(mxA, __shfl_xor(mxA, 32));
  float eAv[2][4];
  float sA = 0.f;
  #pragma unroll
  for (int mt = 0; mt < 2; ++mt)
    #pragma unroll
    for (int i = 0; i < 4; ++i) { eAv[mt][i] = expf(lgA[mt][i] - mxA); sA += eAv[mt][i]; }
  sA += __shfl_xor(sA, 16);
  sA += __shfl_xor(sA, 32);
  const float iA = 1.0f / sA;

  // scatter: out[dst][w*32 + p] += h_ch0 * alpha
  #pragma unroll
  for (int mt = 0; mt < 2; ++mt)
    #pragma unroll
    for (int i = 0; i < 4; ++i) {
      const int r  = mt * 16 + lg * 4 + i;
      const int d1 = e[MEDGE + m0 + r];
      float* bp = out + (size_t)d1 * 256 + w * 32;
      const float aA = eAv[mt][i] * iA;
      atomicAdd(bp + lr,      h3[mt][0][i] * aA);
      atomicAdd(bp + 16 + lr, h3[mt][1][i] * aA);
    }
}

// fp32 -> bf16 weight pre-convert (4 elems/thread)
__global__ __launch_bounds__(256) void cvt_w(const float* __restrict__ src,
                                             ushort* __restrict__ dst, int n4)
{
  const int i = blockIdx.x * 256 + threadIdx.x;
  if (i < n4) {
    floatx4 v = *(const floatx4*)(src + (size_t)i * 4);
    short4v r;
    #pragma unroll
    for (int j = 0; j < 4; ++j) r[j] = (short)f2bf(v[j]);
    *(short4v*)(dst + (size_t)i * 4) = r;
  }
}

// ws layout (bf16 elements)
#define WS_WC 0
#define WS_WI (WS_WC + 512*KC)
#define WS_WO (WS_WI + 1536*DD)

extern "C" void kernel_launch(void* const* d_in, const int* in_sizes, int n_in,
                              void* d_out, int out_size, void* d_ws, size_t ws_size,
                              hipStream_t stream)
{
  (void)in_sizes; (void)n_in; (void)ws_size;
  const float* x  = (const float*)d_in[0];
  const float* ea = (const float*)d_in[1];
  const int*   e  = (const int*)d_in[2];
  const float* Wc = (const float*)d_in[3];
  const float* bc = (const float*)d_in[4];
  const float* Wi = (const float*)d_in[5];
  const float* bi = (const float*)d_in[6];
  const float* Wo = (const float*)d_in[7];
  const float* bo = (const float*)d_in[8];

  ushort* wsb = (ushort*)d_ws;
  ushort* Wcb = wsb + WS_WC;
  ushort* Wib = wsb + WS_WI;
  ushort* Wob = wsb + WS_WO;

  cvt_w<<<dim3((512 * KC / 4 + 255) / 256), dim3(256), 0, stream>>>(Wc, Wcb, 512 * KC / 4);
  cvt_w<<<dim3((1536 * DD / 4 + 255) / 256), dim3(256), 0, stream>>>(Wi, Wib, 1536 * DD / 4);
  cvt_w<<<dim3((512 * DD / 4 + 255) / 256), dim3(256), 0, stream>>>(Wo, Wob, 512 * DD / 4);

  float* out = (float*)d_out;
  hipMemsetAsync(out, 0, (size_t)out_size * sizeof(float), stream);

  nt_fused<<<dim3(NNODE), dim3(512), 0, stream>>>(x, ea, e, Wcb, bc, Wib, bi, Wob, bo, out);
}

// Round 4
// 3307.677 us; speedup vs baseline: 1.1786x; 1.1786x over previous
//
#include <hip/hip_runtime.h>
#include <hip/hip_bf16.h>

#define NNODE 8192
#define DEG   32
#define DIN   256
#define EDIM  64
#define KC    576            // 2*DIN + EDIM
#define DD    512            // internal width D
#define NH    8
#define MEDGE (NNODE*DEG)
#define EXP   520            // 512 + 8 bf16 row pad (16B aligned rows)

typedef __attribute__((ext_vector_type(8))) short short8;
typedef __attribute__((ext_vector_type(4))) short short4v;
typedef __attribute__((ext_vector_type(4))) float floatx4;
typedef __attribute__((ext_vector_type(4))) unsigned int uint4v;
typedef unsigned int u32;

__device__ __forceinline__ ushort f2bf(float f) {
  union { float f; unsigned int i; } v; v.f = f;
  return (ushort)((v.i + 0x7fffu + ((v.i >> 16) & 1u)) >> 16);
}
__device__ __forceinline__ u32 pk2(float a, float b) {
  return (u32)f2bf(a) | ((u32)f2bf(b) << 16);
}
__device__ __forceinline__ float gelu_f(float z) {
  return 0.5f * z * (1.0f + erff(z * 0.70710678118654752f));
}
__device__ __forceinline__ floatx4 zero4() { floatx4 v = {0.f, 0.f, 0.f, 0.f}; return v; }

// load 8 consecutive fp32 -> bf16 half-fragment
__device__ __forceinline__ short8 ld_cvt8(const float* __restrict__ p) {
  floatx4 a = *(const floatx4*)(p);
  floatx4 b = *(const floatx4*)(p + 4);
  short8 r;
  r[0] = (short)f2bf(a[0]); r[1] = (short)f2bf(a[1]);
  r[2] = (short)f2bf(a[2]); r[3] = (short)f2bf(a[3]);
  r[4] = (short)f2bf(b[0]); r[5] = (short)f2bf(b[1]);
  r[6] = (short)f2bf(b[2]); r[7] = (short)f2bf(b[3]);
  return r;
}

#define MFMA16(a, b, c) __builtin_amdgcn_mfma_f32_16x16x32_bf16((a), (b), (c), 0, 0, 0)

// D-layout -> A/B-frag-layout in-register transform.
// Source packed tiles T[tile][p]: lane(lg',lr') dword p = bf16 pair of
// M[tile*16 + lg'*4 + 2p + {0,1}][lr'-col]. Target frag: lane(lg,lr) dword dj =
// M-pair at rows base+8lg+2dj from source lane (2(lg&1)+(dj>>1))*16+lr,
// tile = (lg>>1) among {T0,T1}.
__device__ __forceinline__ u32 bpsel(int a, u32 v0, u32 v1, bool hi) {
  u32 x0 = (u32)__builtin_amdgcn_ds_bpermute(a, (int)v0);
  u32 x1 = (u32)__builtin_amdgcn_ds_bpermute(a, (int)v1);
  return hi ? x1 : x0;
}
__device__ __forceinline__ short8 frag4(int a0, int a1, bool hi,
                                        u32 t00, u32 t01, u32 t10, u32 t11) {
  uint4v r;
  r[0] = bpsel(a0, t00, t10, hi);
  r[1] = bpsel(a0, t01, t11, hi);
  r[2] = bpsel(a1, t00, t10, hi);
  r[3] = bpsel(a1, t01, t11, hi);
  union { uint4v u; short8 s; } c; c.u = r; return c.s;
}

__global__ __launch_bounds__(512, 2) void nt_fused(
    const float* __restrict__ x,  const float* __restrict__ ea,
    const int*   __restrict__ e,
    const ushort* __restrict__ Wc, const float* __restrict__ bc,
    const ushort* __restrict__ Wi, const float* __restrict__ bi,
    const ushort* __restrict__ Wo, const float* __restrict__ bo,
    float* __restrict__ out)
{
  __shared__ __align__(16) ushort sEX[DEG * EXP];   // ex  [32][512] bf16
  __shared__ __align__(16) ushort sAO[DEG * EXP];   // attn out [32][512] bf16

  const int node = blockIdx.x;
  const int m0   = node * DEG;
  const int tid  = threadIdx.x;
  const int w    = tid >> 6;    // wave 0..7 : head w, col slice w*64
  const int l    = tid & 63;
  const int lr   = l & 15;
  const int lg   = l >> 4;

  const int src = e[m0];
  const int dA0 = e[MEDGE + m0 + lr];
  const int dA1 = e[MEDGE + m0 + 16 + lr];

  // ================= GEMM1: ex = gelu(gelu(feat @ Wc^T + bc)) =================
  {
    floatx4 acc0[4], acc1[4];
    #pragma unroll
    for (int nt = 0; nt < 4; ++nt) { acc0[nt] = zero4(); acc1[nt] = zero4(); }

    const float* xsrc = x + (size_t)src * DIN;
    #pragma unroll
    for (int s = 0; s < 8; ++s) {          // k 0..255 : x[src] (both M-tiles equal)
      short8 af = ld_cvt8(xsrc + s * 32 + lg * 8);
      #pragma unroll
      for (int nt = 0; nt < 4; ++nt) {
        const int col = w * 64 + nt * 16 + lr;
        short8 bf = *(const short8*)(Wc + (size_t)col * KC + s * 32 + lg * 8);
        acc0[nt] = MFMA16(af, bf, acc0[nt]);
      }
    }
    #pragma unroll
    for (int nt = 0; nt < 4; ++nt) acc1[nt] = acc0[nt];

    const float* xd0 = x + (size_t)dA0 * DIN;
    const float* xd1 = x + (size_t)dA1 * DIN;
    #pragma unroll
    for (int s = 0; s < 8; ++s) {          // k 256..511 : x[dst]
      short8 a0f = ld_cvt8(xd0 + s * 32 + lg * 8);
      short8 a1f = ld_cvt8(xd1 + s * 32 + lg * 8);
      #pragma unroll
      for (int nt = 0; nt < 4; ++nt) {
        const int col = w * 64 + nt * 16 + lr;
        short8 bf = *(const short8*)(Wc + (size_t)col * KC + 256 + s * 32 + lg * 8);
        acc0[nt] = MFMA16(a0f, bf, acc0[nt]);
        acc1[nt] = MFMA16(a1f, bf, acc1[nt]);
      }
    }
    const float* ea0 = ea + (size_t)(m0 + lr) * EDIM;
    const float* ea1 = ea + (size_t)(m0 + 16 + lr) * EDIM;
    #pragma unroll
    for (int s = 0; s < 2; ++s) {          // k 512..575 : edge_attr
      short8 a0f = ld_cvt8(ea0 + s * 32 + lg * 8);
      short8 a1f = ld_cvt8(ea1 + s * 32 + lg * 8);
      #pragma unroll
      for (int nt = 0; nt < 4; ++nt) {
        const int col = w * 64 + nt * 16 + lr;
        short8 bf = *(const short8*)(Wc + (size_t)col * KC + 512 + s * 32 + lg * 8);
        acc0[nt] = MFMA16(a0f, bf, acc0[nt]);
        acc1[nt] = MFMA16(a1f, bf, acc1[nt]);
      }
    }
    #pragma unroll
    for (int nt = 0; nt < 4; ++nt) {
      const int col = w * 64 + nt * 16 + lr;
      const float bias = bc[col];
      #pragma unroll
      for (int i = 0; i < 4; ++i) {
        sEX[(lg * 4 + i) * EXP + col]      = f2bf(gelu_f(gelu_f(acc0[nt][i] + bias)));
        sEX[(16 + lg * 4 + i) * EXP + col] = f2bf(gelu_f(gelu_f(acc1[nt][i] + bias)));
      }
    }
  }
  __syncthreads();   // barrier #1: sEX complete

  // ================= attention, head w, fully per-wave ======================
  const int qb = w * 64, kb = 512 + w * 64, vb = 1024 + w * 64;

  // ---- phase A: Q' = Wq·ex^T, K' = Wk·ex^T (transposed: rows=qkv-col, cols=edge)
  floatx4 qacc[4][2], kacc[4][2];
  #pragma unroll
  for (int mt = 0; mt < 4; ++mt)
    #pragma unroll
    for (int nt = 0; nt < 2; ++nt) { qacc[mt][nt] = zero4(); kacc[mt][nt] = zero4(); }

  #pragma unroll
  for (int ks = 0; ks < 16; ++ks) {
    short8 ex0 = *(const short8*)(&sEX[lr * EXP + ks * 32 + lg * 8]);
    short8 ex1 = *(const short8*)(&sEX[(16 + lr) * EXP + ks * 32 + lg * 8]);
    #pragma unroll
    for (int mt = 0; mt < 4; ++mt) {
      short8 wq = *(const short8*)(Wi + (size_t)(qb + mt * 16 + lr) * DD + ks * 32 + lg * 8);
      short8 wk = *(const short8*)(Wi + (size_t)(kb + mt * 16 + lr) * DD + ks * 32 + lg * 8);
      qacc[mt][0] = MFMA16(wq, ex0, qacc[mt][0]);
      qacc[mt][1] = MFMA16(wq, ex1, qacc[mt][1]);
      kacc[mt][0] = MFMA16(wk, ex0, kacc[mt][0]);
      kacc[mt][1] = MFMA16(wk, ex1, kacc[mt][1]);
    }
  }
  u32 qp[4][2][2], kp[4][2][2];
  #pragma unroll
  for (int mt = 0; mt < 4; ++mt) {
    float bq[4], bk[4];
    #pragma unroll
    for (int i = 0; i < 4; ++i) {
      bq[i] = bi[qb + mt * 16 + lg * 4 + i];
      bk[i] = bi[kb + mt * 16 + lg * 4 + i];
    }
    #pragma unroll
    for (int nt = 0; nt < 2; ++nt) {
      floatx4 vq = qacc[mt][nt], vk = kacc[mt][nt];
      qp[mt][nt][0] = pk2(vq[0] + bq[0], vq[1] + bq[1]);
      qp[mt][nt][1] = pk2(vq[2] + bq[2], vq[3] + bq[3]);
      kp[mt][nt][0] = pk2(vk[0] + bk[0], vk[1] + bk[1]);
      kp[mt][nt][1] = pk2(vk[2] + bk[2], vk[3] + bk[3]);
    }
  }

  // ---- phase B: V normal (rows=edge, cols=vcol)
  floatx4 vacc[2][4];
  #pragma unroll
  for (int mt = 0; mt < 2; ++mt)
    #pragma unroll
    for (int nt = 0; nt < 4; ++nt) vacc[mt][nt] = zero4();
  #pragma unroll
  for (int ks = 0; ks < 16; ++ks) {
    short8 ex0 = *(const short8*)(&sEX[lr * EXP + ks * 32 + lg * 8]);
    short8 ex1 = *(const short8*)(&sEX[(16 + lr) * EXP + ks * 32 + lg * 8]);
    #pragma unroll
    for (int nt = 0; nt < 4; ++nt) {
      short8 wv = *(const short8*)(Wi + (size_t)(vb + nt * 16 + lr) * DD + ks * 32 + lg * 8);
      vacc[0][nt] = MFMA16(ex0, wv, vacc[0][nt]);
      vacc[1][nt] = MFMA16(ex1, wv, vacc[1][nt]);
    }
  }
  u32 vp[2][4][2];
  #pragma unroll
  for (int nt = 0; nt < 4; ++nt) {
    const float bv = bi[vb + nt * 16 + lr];
    #pragma unroll
    for (int mt = 0; mt < 2; ++mt) {
      floatx4 v = vacc[mt][nt];
      vp[mt][nt][0] = pk2(v[0] + bv, v[1] + bv);
      vp[mt][nt][1] = pk2(v[2] + bv, v[3] + bv);
    }
  }

  // ---- scores' [k-edge][q-edge] = K·Q^T-style, then softmax over k-edges
  const int pa0 = ((2 * (lg & 1)) * 16 + lr) * 4;
  const int pa1 = pa0 + 64;
  const bool hi = ((lg >> 1) & 1) != 0;

  floatx4 sacc[2][2];
  #pragma unroll
  for (int mt = 0; mt < 2; ++mt)
    #pragma unroll
    for (int nt = 0; nt < 2; ++nt) sacc[mt][nt] = zero4();
  #pragma unroll
  for (int kt = 0; kt < 2; ++kt) {
    short8 afr0 = frag4(pa0, pa1, hi, kp[2*kt][0][0], kp[2*kt][0][1], kp[2*kt+1][0][0], kp[2*kt+1][0][1]);
    short8 afr1 = frag4(pa0, pa1, hi, kp[2*kt][1][0], kp[2*kt][1][1], kp[2*kt+1][1][0], kp[2*kt+1][1][1]);
    short8 bfr0 = frag4(pa0, pa1, hi, qp[2*kt][0][0], qp[2*kt][0][1], qp[2*kt+1][0][0], qp[2*kt+1][0][1]);
    short8 bfr1 = frag4(pa0, pa1, hi, qp[2*kt][1][0], qp[2*kt][1][1], qp[2*kt+1][1][0], qp[2*kt+1][1][1]);
    sacc[0][0] = MFMA16(afr0, bfr0, sacc[0][0]);
    sacc[0][1] = MFMA16(afr0, bfr1, sacc[0][1]);
    sacc[1][0] = MFMA16(afr1, bfr0, sacc[1][0]);
    sacc[1][1] = MFMA16(afr1, bfr1, sacc[1][1]);
  }

  u32 pp[2][2][2];   // [ke-tile][qe-tile][p]
  #pragma unroll
  for (int nt = 0; nt < 2; ++nt) {
    float s[2][4];
    float mx = -1e30f;
    #pragma unroll
    for (int mt = 0; mt < 2; ++mt)
      #pragma unroll
      for (int i = 0; i < 4; ++i) {
        s[mt][i] = sacc[mt][nt][i] * 0.125f;
        mx = fmaxf(mx, s[mt][i]);
      }
    mx = fmaxf(mx, __shfl_xor(mx, 16));
    mx = fmaxf(mx, __shfl_xor(mx, 32));
    float sm = 0.f;
    #pragma unroll
    for (int mt = 0; mt < 2; ++mt)
      #pragma unroll
      for (int i = 0; i < 4; ++i) { s[mt][i] = expf(s[mt][i] - mx); sm += s[mt][i]; }
    sm += __shfl_xor(sm, 16);
    sm += __shfl_xor(sm, 32);
    const float inv = 1.0f / sm;
    #pragma unroll
    for (int mt = 0; mt < 2; ++mt) {
      pp[mt][nt][0] = pk2(s[mt][0] * inv, s[mt][1] * inv);
      pp[mt][nt][1] = pk2(s[mt][2] * inv, s[mt][3] * inv);
    }
  }

  // ---- PV: o[q-edge][vcol] = P·V -> sAO cols [w*64, w*64+64)
  {
    short8 paf[2], vbf[4];
    #pragma unroll
    for (int mt = 0; mt < 2; ++mt)
      paf[mt] = frag4(pa0, pa1, hi, pp[0][mt][0], pp[0][mt][1], pp[1][mt][0], pp[1][mt][1]);
    #pragma unroll
    for (int nt = 0; nt < 4; ++nt)
      vbf[nt] = frag4(pa0, pa1, hi, vp[0][nt][0], vp[0][nt][1], vp[1][nt][0], vp[1][nt][1]);
    #pragma unroll
    for (int mt = 0; mt < 2; ++mt)
      #pragma unroll
      for (int nt = 0; nt < 4; ++nt) {
        floatx4 o = MFMA16(paf[mt], vbf[nt], zero4());
        #pragma unroll
        for (int i = 0; i < 4; ++i)
          sAO[(mt * 16 + lg * 4 + i) * EXP + w * 64 + nt * 16 + lr] = f2bf(o[i]);
      }
  }
  __syncthreads();   // barrier #2: sAO complete

  // ================= GEMM3: h = gelu(AO @ Wo^T + bo) + weighted-mean agg =====
  floatx4 h3[2][4];
  #pragma unroll
  for (int mt = 0; mt < 2; ++mt)
    #pragma unroll
    for (int nt = 0; nt < 4; ++nt) h3[mt][nt] = zero4();
  #pragma unroll
  for (int ks = 0; ks < 16; ++ks) {
    short8 a0f = *(const short8*)(&sAO[lr * EXP + ks * 32 + lg * 8]);
    short8 a1f = *(const short8*)(&sAO[(16 + lr) * EXP + ks * 32 + lg * 8]);
    #pragma unroll
    for (int nt = 0; nt < 4; ++nt) {
      const int col = w * 64 + nt * 16 + lr;
      short8 bf = *(const short8*)(Wo + (size_t)col * DD + ks * 32 + lg * 8);
      h3[0][nt] = MFMA16(a0f, bf, h3[0][nt]);
      h3[1][nt] = MFMA16(a1f, bf, h3[1][nt]);
    }
  }
  #pragma unroll
  for (int nt = 0; nt < 4; ++nt) {
    const float bias = bo[w * 64 + nt * 16 + lr];
    #pragma unroll
    for (int i = 0; i < 4; ++i) {
      h3[0][nt][i] = gelu_f(h3[0][nt][i] + bias);
      h3[1][nt][i] = gelu_f(h3[1][nt][i] + bias);
    }
  }
  // logits (head w) = mean over ch1 (tiles 2,3): reduce across lr lanes
  float lgA[2][4];
  #pragma unroll
  for (int mt = 0; mt < 2; ++mt)
    #pragma unroll
    for (int i = 0; i < 4; ++i) {
      float tA = h3[mt][2][i] + h3[mt][3][i];
      #pragma unroll
      for (int d2 = 1; d2 < 16; d2 <<= 1) tA += __shfl_xor(tA, d2);
      lgA[mt][i] = tA * (1.0f / 32.0f);
    }
  // alpha = softmax over the 32 edges (per head)
  float mxA = -1e30f;
  #pragma unroll
  for (int mt = 0; mt < 2; ++mt)
    #pragma unroll
    for (int i = 0; i < 4; ++i) mxA = fmaxf(mxA, lgA[mt][i]);
  mxA = fmaxf(mxA, __shfl_xor(mxA, 16));
  mxA = fmaxf(mxA, __shfl_xor(mxA, 32));
  float eAv[2][4];
  float sA = 0.f;
  #pragma unroll
  for (int mt = 0; mt < 2; ++mt)
    #pragma unroll
    for (int i = 0; i < 4; ++i) { eAv[mt][i] = expf(lgA[mt][i] - mxA); sA += eAv[mt][i]; }
  sA += __shfl_xor(sA, 16);
  sA += __shfl_xor(sA, 32);
  const float iA = 1.0f / sA;

  // scatter: out[dst][w*32 + p] += h_ch0 * alpha
  #pragma unroll
  for (int mt = 0; mt < 2; ++mt)
    #pragma unroll
    for (int i = 0; i < 4; ++i) {
      const int r  = mt * 16 + lg * 4 + i;
      const int d1 = e[MEDGE + m0 + r];
      float* bp = out + (size_t)d1 * 256 + w * 32;
      const float aA = eAv[mt][i] * iA;
      atomicAdd(bp + lr,      h3[mt][0][i] * aA);
      atomicAdd(bp + 16 + lr, h3[mt][1][i] * aA);
    }
}

// fp32 -> bf16 weight pre-convert (4 elems/thread)
__global__ __launch_bounds__(256) void cvt_w(const float* __restrict__ src,
                                             ushort* __restrict__ dst, int n4)
{
  const int i = blockIdx.x * 256 + threadIdx.x;
  if (i < n4) {
    floatx4 v = *(const floatx4*)(src + (size_t)i * 4);
    short4v r;
    #pragma unroll
    for (int j = 0; j < 4; ++j) r[j] = (short)f2bf(v[j]);
    *(short4v*)(dst + (size_t)i * 4) = r;
  }
}

// ws layout (bf16 elements)
#define WS_WC 0
#define WS_WI (WS_WC + 512*KC)
#define WS_WO (WS_WI + 1536*DD)

extern "C" void kernel_launch(void* const* d_in, const int* in_sizes, int n_in,
                              void* d_out, int out_size, void* d_ws, size_t ws_size,
                              hipStream_t stream)
{
  (void)in_sizes; (void)n_in; (void)ws_size;
  const float* x  = (const float*)d_in[0];
  const float* ea = (const float*)d_in[1];
  const int*   e  = (const int*)d_in[2];
  const float* Wc = (const float*)d_in[3];
  const float* bc = (const float*)d_in[4];
  const float* Wi = (const float*)d_in[5];
  const float* bi = (const float*)d_in[6];
  const float* Wo = (const float*)d_in[7];
  const float* bo = (const float*)d_in[8];

  ushort* wsb = (ushort*)d_ws;
  ushort* Wcb = wsb + WS_WC;
  ushort* Wib = wsb + WS_WI;
  ushort* Wob = wsb + WS_WO;

  cvt_w<<<dim3((512 * KC / 4 + 255) / 256), dim3(256), 0, stream>>>(Wc, Wcb, 512 * KC / 4);
  cvt_w<<<dim3((1536 * DD / 4 + 255) / 256), dim3(256), 0, stream>>>(Wi, Wib, 1536 * DD / 4);
  cvt_w<<<dim3((512 * DD / 4 + 255) / 256), dim3(256), 0, stream>>>(Wo, Wob, 512 * DD / 4);

  float* out = (float*)d_out;
  hipMemsetAsync(out, 0, (size_t)out_size * sizeof(float), stream);

  nt_fused<<<dim3(NNODE), dim3(512), 0, stream>>>(x, ea, e, Wcb, bc, Wib, bi, Wob, bo, out);
}